// Round 13
// baseline (317.379 us; speedup 1.0000x reference)
//
#include <hip/hip_runtime.h>
#include <hip/hip_bf16.h>

#define THREADS 256
#define BSHIFT 9              // 512 nodes per coarse bucket; NB = ceil(N/512) <= 256
#define BIN_CHUNK 4096        // edges per k_bin block (16/thread)

typedef __attribute__((ext_vector_type(8))) short bf16x8;
typedef __attribute__((ext_vector_type(4))) float f32x4;

// ---------------- helpers ----------------

__device__ inline unsigned short f2bf(float f) {  // round-to-nearest-even
    unsigned int u = __float_as_uint(f);
    unsigned int r = (u + 0x7fffu + ((u >> 16) & 1u)) >> 16;
    return (unsigned short)r;
}

__device__ inline unsigned int pack_bf2(float x, float y) {
    return (unsigned int)f2bf(x) | ((unsigned int)f2bf(y) << 16);
}

__device__ inline float2 bf2_to_f2(unsigned int u) {  // low bf16 -> x, high bf16 -> y
    float2 r;
    r.x = __uint_as_float(u << 16);
    r.y = __uint_as_float(u & 0xffff0000u);
    return r;
}

__device__ inline unsigned short bf_relu(unsigned short v) {
    return (v & 0x8000u) ? (unsigned short)0 : v;
}

// ---------------- CSR build: padded bucket windows, packed 4B edges ----------------
// Edge record: (dst_local:9 bits << 23) | src. bcur holds zero-based counts
// (memset to 0); absolute position = b*cap + count.

__global__ __launch_bounds__(256) void k_bin(const int* __restrict__ src,
                                             const int* __restrict__ dst,
                                             int* __restrict__ bcur,
                                             unsigned int* __restrict__ binned,
                                             int E, int NB, int cap) {
    __shared__ int bcnt[256];
    __shared__ int bres[256];
    int t = threadIdx.x;
    bcnt[t] = 0;
    __syncthreads();
    int base = blockIdx.x * BIN_CHUNK;
    int sv[16], dv[16];
#pragma unroll
    for (int i = 0; i < 16; ++i) {
        int e = base + t + i * 256;
        if (e < E) {
            sv[i] = src[e];
            dv[i] = dst[e];
            atomicAdd(&bcnt[dv[i] >> BSHIFT], 1);
        } else {
            dv[i] = -1;
        }
    }
    __syncthreads();
    if (t < NB) {
        int old = bcnt[t] ? atomicAdd(&bcur[t], bcnt[t]) : 0;
        bres[t] = t * cap + old;
    }
    __syncthreads();
#pragma unroll
    for (int i = 0; i < 16; ++i) {
        if (dv[i] >= 0) {
            int b = dv[i] >> BSHIFT;
            int pos = atomicAdd(&bres[b], 1);
            if (pos < (b + 1) * cap)  // overflow guard (statistically never trips)
                binned[pos] = ((unsigned int)(dv[i] & 511) << 23) | (unsigned int)sv[i];
        }
    }
}

// per-bucket: histogram -> intra-bucket scan -> rp/deg/dinv, then place srcs
// into eperm via LDS cursors. One block per bucket; window re-read is L2-hot.
__global__ __launch_bounds__(256) void k_node_place(const unsigned int* __restrict__ binned,
                                                    const int* __restrict__ bcur, int cap,
                                                    int* __restrict__ rp,
                                                    int* __restrict__ deg,
                                                    float* __restrict__ dinv,
                                                    int* __restrict__ eperm, int N) {
    __shared__ int lc[512];
    __shared__ int s[256];
    int b = blockIdx.x;
    int t = threadIdx.x;
    int beg = b * cap;
    int end = beg + min(bcur[b], cap);
    int d0 = b << BSHIFT;
    lc[t] = 0;
    lc[t + 256] = 0;
    __syncthreads();
    for (int j = beg + t; j < end; j += 256) atomicAdd(&lc[binned[j] >> 23], 1);
    __syncthreads();
    int a = lc[2 * t], c = lc[2 * t + 1];
    int pair = a + c;
    s[t] = pair;
    __syncthreads();
    for (int off = 1; off < 256; off <<= 1) {
        int add = (t >= off) ? s[t - off] : 0;
        __syncthreads();
        s[t] += add;
        __syncthreads();
    }
    int excl = s[t] - pair;
    int st0 = beg + excl, st1 = st0 + a;
    int node0 = d0 + 2 * t;
    if (node0 < N) {
        rp[node0] = st0;
        deg[node0] = a;
        dinv[node0] = rsqrtf((float)a + 1.0f);  // +1 = self-loop
    }
    if (node0 + 1 < N) {
        rp[node0 + 1] = st1;
        deg[node0 + 1] = c;
        dinv[node0 + 1] = rsqrtf((float)c + 1.0f);
    }
    __syncthreads();
    lc[2 * t] = st0;               // repurpose lc as placement cursors
    lc[2 * t + 1] = st1;
    __syncthreads();
    for (int j = beg + t; j < end; j += 256) {
        unsigned int p = binned[j];
        int pos = atomicAdd(&lc[p >> 23], 1);
        eperm[pos] = (int)(p & 0x7fffffu);
    }
}

// ---------------- MFMA GEMM: C[M x N](bf16) = dinv[row] * (A[M x 128] @ W[128 x N]) ----
// M-tile 128 (amortizes full-W staging over 2x rows vs the old 64-row tile).

template <int N, bool ABF16_RELU>
__global__ __launch_bounds__(256) void k_gemm_mfma(const void* __restrict__ Av,
                                                   const float* __restrict__ W,
                                                   const float* __restrict__ dinv,
                                                   unsigned short* __restrict__ C, int M) {
    static_assert(N == 64 || N == 128, "N must be 64 or 128");
    constexpr int NT = N / 64;
    constexpr int KP = 136;
    __shared__ short As[128 * KP];
    __shared__ short Bs[N * KP];
    __shared__ float sDin[128];

    const int t = threadIdx.x;
    const int m0 = blockIdx.x * 128;

    {   // stage A 128x128 -> bf16 (relu'd bf16 or converted fp32)
        int ar = t >> 5;
        int ac = (t & 31) * 4;
#pragma unroll
        for (int rb = 0; rb < 128; rb += 8) {
            int lrow = rb + ar;
            int row = m0 + lrow;
            ushort4 sv = make_ushort4(0, 0, 0, 0);
            if (ABF16_RELU) {
                if (row < M) {
                    ushort4 u = *(const ushort4*)((const unsigned short*)Av + (size_t)row * 128 + ac);
                    sv.x = bf_relu(u.x); sv.y = bf_relu(u.y);
                    sv.z = bf_relu(u.z); sv.w = bf_relu(u.w);
                }
            } else {
                if (row < M) {
                    float4 v = *(const float4*)((const float*)Av + (size_t)row * 128 + ac);
                    sv.x = f2bf(v.x); sv.y = f2bf(v.y); sv.z = f2bf(v.z); sv.w = f2bf(v.w);
                }
            }
            *(ushort4*)&As[lrow * KP + ac] = sv;
        }
    }
    {   // stage W transposed: Bs[n][k] <- W[k][n] (fp32 -> bf16)
        constexpr int TPR = N / 4;
        constexpr int KPI = 256 / TPR;
        int bk = t / TPR;
        int bn = (t % TPR) * 4;
#pragma unroll
        for (int kb = 0; kb < 128; kb += KPI) {
            int k = kb + bk;
            float4 wv = *(const float4*)(W + (size_t)k * N + bn);
            Bs[(bn + 0) * KP + k] = f2bf(wv.x);
            Bs[(bn + 1) * KP + k] = f2bf(wv.y);
            Bs[(bn + 2) * KP + k] = f2bf(wv.z);
            Bs[(bn + 3) * KP + k] = f2bf(wv.w);
        }
    }
    if (t < 128) sDin[t] = (m0 + t < M) ? dinv[m0 + t] : 1.0f;
    __syncthreads();

    const int w = t >> 6;
    const int lane = t & 63;
    const int lm = lane & 15;
    const int qd = lane >> 4;
    const int n0w = w * 16 * NT;

    f32x4 acc[8][NT];
#pragma unroll
    for (int mi = 0; mi < 8; ++mi)
#pragma unroll
        for (int ni = 0; ni < NT; ++ni) acc[mi][ni] = (f32x4){0.f, 0.f, 0.f, 0.f};

#pragma unroll
    for (int ks = 0; ks < 4; ++ks) {
        bf16x8 a[8], b[NT];
#pragma unroll
        for (int mi = 0; mi < 8; ++mi)
            a[mi] = *(const bf16x8*)&As[(mi * 16 + lm) * KP + ks * 32 + qd * 8];
#pragma unroll
        for (int ni = 0; ni < NT; ++ni)
            b[ni] = *(const bf16x8*)&Bs[(n0w + ni * 16 + lm) * KP + ks * 32 + qd * 8];
#pragma unroll
        for (int mi = 0; mi < 8; ++mi)
#pragma unroll
            for (int ni = 0; ni < NT; ++ni)
                acc[mi][ni] = __builtin_amdgcn_mfma_f32_16x16x32_bf16(a[mi], b[ni], acc[mi][ni], 0, 0, 0);
    }

#pragma unroll
    for (int mi = 0; mi < 8; ++mi) {
#pragma unroll
        for (int ni = 0; ni < NT; ++ni) {
            int col = n0w + ni * 16 + lm;
#pragma unroll
            for (int r = 0; r < 4; ++r) {
                int lrow = mi * 16 + qd * 4 + r;
                int row = m0 + lrow;
                if (row < M) C[(size_t)row * N + col] = f2bf(sDin[lrow] * acc[mi][ni][r]);
            }
        }
    }
}

// ---------------- CSR gather: out[d] = dinv[d] * (sum_in h'[src] + h'[d]) + b --------
// rp/deg addressing (padded windows are gapped). Unroll-16 + 8/4/2/1 ladder.

__global__ __launch_bounds__(256) void k_gather128(const int* __restrict__ rp,
                                                   const int* __restrict__ deg,
                                                   const int* __restrict__ eperm,
                                                   const float* __restrict__ dinv,
                                                   const unsigned int* __restrict__ h,  // bf16x2
                                                   const float* __restrict__ bias,
                                                   unsigned int* __restrict__ out,      // bf16x2
                                                   int n) {
    int node = blockIdx.x * 4 + (threadIdx.x >> 6);
    if (node >= n) return;
    int lane = threadIdx.x & 63;
    int beg = rp[node];
    int end = beg + deg[node];
    float2 acc = bf2_to_f2(h[(size_t)node * 64 + lane]);  // self h'[d]
    int j = beg;
    for (; j + 16 <= end; j += 16) {
        float2 a0 = make_float2(0.f, 0.f), a1 = a0;
#pragma unroll
        for (int u = 0; u < 2; ++u) {
            int e0 = eperm[j + 8 * u],     e1 = eperm[j + 8 * u + 1];
            int e2 = eperm[j + 8 * u + 2], e3 = eperm[j + 8 * u + 3];
            int e4 = eperm[j + 8 * u + 4], e5 = eperm[j + 8 * u + 5];
            int e6 = eperm[j + 8 * u + 6], e7 = eperm[j + 8 * u + 7];
            float2 v0 = bf2_to_f2(h[(size_t)e0 * 64 + lane]);
            float2 v1 = bf2_to_f2(h[(size_t)e1 * 64 + lane]);
            float2 v2 = bf2_to_f2(h[(size_t)e2 * 64 + lane]);
            float2 v3 = bf2_to_f2(h[(size_t)e3 * 64 + lane]);
            float2 v4 = bf2_to_f2(h[(size_t)e4 * 64 + lane]);
            float2 v5 = bf2_to_f2(h[(size_t)e5 * 64 + lane]);
            float2 v6 = bf2_to_f2(h[(size_t)e6 * 64 + lane]);
            float2 v7 = bf2_to_f2(h[(size_t)e7 * 64 + lane]);
            float2* dst2 = u ? &a1 : &a0;
            dst2->x += ((v0.x + v1.x) + (v2.x + v3.x)) + ((v4.x + v5.x) + (v6.x + v7.x));
            dst2->y += ((v0.y + v1.y) + (v2.y + v3.y)) + ((v4.y + v5.y) + (v6.y + v7.y));
        }
        acc.x += a0.x + a1.x;
        acc.y += a0.y + a1.y;
    }
    if (j + 8 <= end) {
        int e0 = eperm[j],     e1 = eperm[j + 1], e2 = eperm[j + 2], e3 = eperm[j + 3];
        int e4 = eperm[j + 4], e5 = eperm[j + 5], e6 = eperm[j + 6], e7 = eperm[j + 7];
        float2 v0 = bf2_to_f2(h[(size_t)e0 * 64 + lane]);
        float2 v1 = bf2_to_f2(h[(size_t)e1 * 64 + lane]);
        float2 v2 = bf2_to_f2(h[(size_t)e2 * 64 + lane]);
        float2 v3 = bf2_to_f2(h[(size_t)e3 * 64 + lane]);
        float2 v4 = bf2_to_f2(h[(size_t)e4 * 64 + lane]);
        float2 v5 = bf2_to_f2(h[(size_t)e5 * 64 + lane]);
        float2 v6 = bf2_to_f2(h[(size_t)e6 * 64 + lane]);
        float2 v7 = bf2_to_f2(h[(size_t)e7 * 64 + lane]);
        acc.x += ((v0.x + v1.x) + (v2.x + v3.x)) + ((v4.x + v5.x) + (v6.x + v7.x));
        acc.y += ((v0.y + v1.y) + (v2.y + v3.y)) + ((v4.y + v5.y) + (v6.y + v7.y));
        j += 8;
    }
    if (j + 4 <= end) {
        int e0 = eperm[j], e1 = eperm[j + 1], e2 = eperm[j + 2], e3 = eperm[j + 3];
        float2 v0 = bf2_to_f2(h[(size_t)e0 * 64 + lane]);
        float2 v1 = bf2_to_f2(h[(size_t)e1 * 64 + lane]);
        float2 v2 = bf2_to_f2(h[(size_t)e2 * 64 + lane]);
        float2 v3 = bf2_to_f2(h[(size_t)e3 * 64 + lane]);
        acc.x += (v0.x + v1.x) + (v2.x + v3.x);
        acc.y += (v0.y + v1.y) + (v2.y + v3.y);
        j += 4;
    }
    if (j + 2 <= end) {
        int e0 = eperm[j], e1 = eperm[j + 1];
        float2 v0 = bf2_to_f2(h[(size_t)e0 * 64 + lane]);
        float2 v1 = bf2_to_f2(h[(size_t)e1 * 64 + lane]);
        acc.x += v0.x + v1.x;
        acc.y += v0.y + v1.y;
        j += 2;
    }
    if (j < end) {
        float2 v = bf2_to_f2(h[(size_t)eperm[j] * 64 + lane]);
        acc.x += v.x;
        acc.y += v.y;
    }
    float dv = dinv[node];
    float2 bv = ((const float2*)bias)[lane];
    out[(size_t)node * 64 + lane] = pack_bf2(dv * acc.x + bv.x, dv * acc.y + bv.y);
}

// 64-wide: half-waves split the edge list (even/odd); unroll 8 per half.
__global__ __launch_bounds__(256) void k_gather64(const int* __restrict__ rp,
                                                  const int* __restrict__ deg,
                                                  const int* __restrict__ eperm,
                                                  const float* __restrict__ dinv,
                                                  const unsigned int* __restrict__ h,  // bf16x2
                                                  const float* __restrict__ bias,
                                                  float* __restrict__ out, int n) {
    int node = blockIdx.x * 4 + (threadIdx.x >> 6);
    if (node >= n) return;
    int t = threadIdx.x;
    int l32 = t & 31;
    int half = (t >> 5) & 1;
    int beg = rp[node];
    int end = beg + deg[node];
    float2 acc = make_float2(0.f, 0.f);
    if (half == 0) acc = bf2_to_f2(h[(size_t)node * 32 + l32]);  // self h'[d]
    int j = beg + half;
    for (; j + 14 < end; j += 16) {
        int e0 = eperm[j],      e1 = eperm[j + 2],  e2 = eperm[j + 4],  e3 = eperm[j + 6];
        int e4 = eperm[j + 8],  e5 = eperm[j + 10], e6 = eperm[j + 12], e7 = eperm[j + 14];
        float2 v0 = bf2_to_f2(h[(size_t)e0 * 32 + l32]);
        float2 v1 = bf2_to_f2(h[(size_t)e1 * 32 + l32]);
        float2 v2 = bf2_to_f2(h[(size_t)e2 * 32 + l32]);
        float2 v3 = bf2_to_f2(h[(size_t)e3 * 32 + l32]);
        float2 v4 = bf2_to_f2(h[(size_t)e4 * 32 + l32]);
        float2 v5 = bf2_to_f2(h[(size_t)e5 * 32 + l32]);
        float2 v6 = bf2_to_f2(h[(size_t)e6 * 32 + l32]);
        float2 v7 = bf2_to_f2(h[(size_t)e7 * 32 + l32]);
        acc.x += ((v0.x + v1.x) + (v2.x + v3.x)) + ((v4.x + v5.x) + (v6.x + v7.x));
        acc.y += ((v0.y + v1.y) + (v2.y + v3.y)) + ((v4.y + v5.y) + (v6.y + v7.y));
    }
    if (j + 6 < end) {
        int e0 = eperm[j], e1 = eperm[j + 2], e2 = eperm[j + 4], e3 = eperm[j + 6];
        float2 v0 = bf2_to_f2(h[(size_t)e0 * 32 + l32]);
        float2 v1 = bf2_to_f2(h[(size_t)e1 * 32 + l32]);
        float2 v2 = bf2_to_f2(h[(size_t)e2 * 32 + l32]);
        float2 v3 = bf2_to_f2(h[(size_t)e3 * 32 + l32]);
        acc.x += (v0.x + v1.x) + (v2.x + v3.x);
        acc.y += (v0.y + v1.y) + (v2.y + v3.y);
        j += 8;
    }
    for (; j < end; j += 2) {
        float2 v = bf2_to_f2(h[(size_t)eperm[j] * 32 + l32]);
        acc.x += v.x;
        acc.y += v.y;
    }
    acc.x += __shfl_xor(acc.x, 32);
    acc.y += __shfl_xor(acc.y, 32);
    if (half == 0) {
        float dv = dinv[node];
        float2 bv = ((const float2*)bias)[l32];
        ((float2*)out)[(size_t)node * 32 + l32] =
            make_float2(dv * acc.x + bv.x, dv * acc.y + bv.y);
    }
}

// ---------------- launch ----------------

extern "C" void kernel_launch(void* const* d_in, const int* in_sizes, int n_in,
                              void* d_out, int out_size, void* d_ws, size_t ws_size,
                              hipStream_t stream) {
    const float* x  = (const float*)d_in[0];
    const int*   ei = (const int*)d_in[1];
    const float* W1 = (const float*)d_in[2];
    const float* b1 = (const float*)d_in[3];
    const float* W2 = (const float*)d_in[4];
    const float* b2 = (const float*)d_in[5];
    float* out = (float*)d_out;

    const int N = in_sizes[0] / 128;
    const int E = in_sizes[1] / 2;
    const int* src = ei;
    const int* dst = ei + E;
    const int NB = (N + 511) >> BSHIFT;                          // coarse buckets (<= 256)
    const int cap = (E + NB - 1) / NB + ((E / NB) >> 2) + 1024;  // padded window (mean+25%+1024)

    char* ws = (char*)d_ws;
    size_t off = 0;
    auto carve = [&](size_t bytes) -> void* {
        void* p = ws + off;
        off = (off + bytes + 255) & ~(size_t)255;
        return p;
    };
    float* dinv = (float*)carve((size_t)N * 4);
    int*   rp   = (int*)carve((size_t)N * 4);
    int*   deg  = (int*)carve((size_t)N * 4);
    int*   bcur = (int*)carve(256 * 4);
    unsigned int* binned = (unsigned int*)carve((size_t)NB * cap * 4);  // packed (dlocal,src)
    int*   eperm = (int*)carve((size_t)NB * cap * 4);                   // src, bucket-windowed
    unsigned short* h    = (unsigned short*)carve((size_t)N * 128 * 2); // bf16 h' = dinv*(x@W1)
    unsigned short* hagg = (unsigned short*)carve((size_t)N * 128 * 2); // bf16 layer-1 out
    unsigned short* h2 = h;  // h dead after gather128

    const int gMm = (N + 127) / 128;
    const int ngrp = (N + 3) / 4;

    // ---- CSR build (2 kernels + 1 memset, padded windows) ----
    hipMemsetAsync(bcur, 0, 256 * sizeof(int), stream);
    k_bin<<<(E + BIN_CHUNK - 1) / BIN_CHUNK, THREADS, 0, stream>>>(src, dst, bcur, binned, E, NB, cap);
    k_node_place<<<NB, THREADS, 0, stream>>>(binned, bcur, cap, rp, deg, dinv, eperm, N);

    // ---- layer 1 ----
    k_gemm_mfma<128, false><<<gMm, THREADS, 0, stream>>>(x, W1, dinv, h, N);
    k_gather128<<<ngrp, THREADS, 0, stream>>>(rp, deg, eperm, dinv, (const unsigned int*)h, b1,
                                              (unsigned int*)hagg, N);

    // ---- layer 2 ----
    k_gemm_mfma<64, true><<<gMm, THREADS, 0, stream>>>(hagg, W2, dinv, h2, N);
    k_gather64<<<ngrp, THREADS, 0, stream>>>(rp, deg, eperm, dinv, (const unsigned int*)h2, b2, out, N);
}

// Round 14
// 307.095 us; speedup vs baseline: 1.0335x; 1.0335x over previous
//
#include <hip/hip_runtime.h>
#include <hip/hip_bf16.h>

#define THREADS 256
#define BSHIFT 9              // 512 nodes per coarse bucket; NB = ceil(N/512) <= 256
#define BIN_CHUNK 4096        // edges per k_bin block (16/thread)

typedef __attribute__((ext_vector_type(8))) short bf16x8;
typedef __attribute__((ext_vector_type(4))) float f32x4;

// ---------------- helpers ----------------

__device__ inline unsigned short f2bf(float f) {  // round-to-nearest-even
    unsigned int u = __float_as_uint(f);
    unsigned int r = (u + 0x7fffu + ((u >> 16) & 1u)) >> 16;
    return (unsigned short)r;
}

__device__ inline unsigned int pack_bf2(float x, float y) {
    return (unsigned int)f2bf(x) | ((unsigned int)f2bf(y) << 16);
}

__device__ inline float2 bf2_to_f2(unsigned int u) {  // low bf16 -> x, high bf16 -> y
    float2 r;
    r.x = __uint_as_float(u << 16);
    r.y = __uint_as_float(u & 0xffff0000u);
    return r;
}

__device__ inline unsigned short bf_relu(unsigned short v) {
    return (v & 0x8000u) ? (unsigned short)0 : v;
}

// ---------------- CSR build: padded bucket windows, packed 4B edges ----------------
// Edge record: (dst_local:9 bits << 23) | src. bcur holds zero-based counts
// (memset to 0); absolute position = b*cap + count.

__global__ __launch_bounds__(256) void k_bin(const int* __restrict__ src,
                                             const int* __restrict__ dst,
                                             int* __restrict__ bcur,
                                             unsigned int* __restrict__ binned,
                                             int E, int NB, int cap) {
    __shared__ int bcnt[256];
    __shared__ int bres[256];
    int t = threadIdx.x;
    bcnt[t] = 0;
    __syncthreads();
    int base = blockIdx.x * BIN_CHUNK;
    int sv[16], dv[16];
#pragma unroll
    for (int i = 0; i < 16; ++i) {
        int e = base + t + i * 256;
        if (e < E) {
            sv[i] = src[e];
            dv[i] = dst[e];
            atomicAdd(&bcnt[dv[i] >> BSHIFT], 1);
        } else {
            dv[i] = -1;
        }
    }
    __syncthreads();
    if (t < NB) {
        int old = bcnt[t] ? atomicAdd(&bcur[t], bcnt[t]) : 0;
        bres[t] = t * cap + old;
    }
    __syncthreads();
#pragma unroll
    for (int i = 0; i < 16; ++i) {
        if (dv[i] >= 0) {
            int b = dv[i] >> BSHIFT;
            int pos = atomicAdd(&bres[b], 1);
            if (pos < (b + 1) * cap)  // overflow guard (statistically never trips)
                binned[pos] = ((unsigned int)(dv[i] & 511) << 23) | (unsigned int)sv[i];
        }
    }
}

// per-bucket: histogram -> intra-bucket scan -> rp/deg/dinv, then place srcs
// into eperm via LDS cursors. One block per bucket; window re-read is L2-hot.
__global__ __launch_bounds__(256) void k_node_place(const unsigned int* __restrict__ binned,
                                                    const int* __restrict__ bcur, int cap,
                                                    int* __restrict__ rp,
                                                    int* __restrict__ deg,
                                                    float* __restrict__ dinv,
                                                    int* __restrict__ eperm, int N) {
    __shared__ int lc[512];
    __shared__ int s[256];
    int b = blockIdx.x;
    int t = threadIdx.x;
    int beg = b * cap;
    int end = beg + min(bcur[b], cap);
    int d0 = b << BSHIFT;
    lc[t] = 0;
    lc[t + 256] = 0;
    __syncthreads();
    for (int j = beg + t; j < end; j += 256) atomicAdd(&lc[binned[j] >> 23], 1);
    __syncthreads();
    int a = lc[2 * t], c = lc[2 * t + 1];
    int pair = a + c;
    s[t] = pair;
    __syncthreads();
    for (int off = 1; off < 256; off <<= 1) {
        int add = (t >= off) ? s[t - off] : 0;
        __syncthreads();
        s[t] += add;
        __syncthreads();
    }
    int excl = s[t] - pair;
    int st0 = beg + excl, st1 = st0 + a;
    int node0 = d0 + 2 * t;
    if (node0 < N) {
        rp[node0] = st0;
        deg[node0] = a;
        dinv[node0] = rsqrtf((float)a + 1.0f);  // +1 = self-loop
    }
    if (node0 + 1 < N) {
        rp[node0 + 1] = st1;
        deg[node0 + 1] = c;
        dinv[node0 + 1] = rsqrtf((float)c + 1.0f);
    }
    __syncthreads();
    lc[2 * t] = st0;               // repurpose lc as placement cursors
    lc[2 * t + 1] = st1;
    __syncthreads();
    for (int j = beg + t; j < end; j += 256) {
        unsigned int p = binned[j];
        int pos = atomicAdd(&lc[p >> 23], 1);
        eperm[pos] = (int)(p & 0x7fffffu);
    }
}

// ---------------- MFMA GEMM: C[M x N](bf16) = dinv[row] * (A[M x 128] @ W[128 x N]) ----
// M-tile 64 (36 KB LDS -> 4 blocks/CU; staging is latency-bound and needs the
// occupancy — the 128-tile variant at 2 blocks/CU measured slower, R13).

template <int N, bool ABF16_RELU>
__global__ __launch_bounds__(256) void k_gemm_mfma(const void* __restrict__ Av,
                                                   const float* __restrict__ W,
                                                   const float* __restrict__ dinv,
                                                   unsigned short* __restrict__ C, int M) {
    static_assert(N == 64 || N == 128, "N must be 64 or 128");
    constexpr int NT = N / 64;
    constexpr int KP = 136;
    __shared__ short As[64 * KP];
    __shared__ short Bs[N * KP];
    __shared__ float sDin[64];

    const int t = threadIdx.x;
    const int m0 = blockIdx.x * 64;

    {
        int ar = t >> 5;
        int ac = (t & 31) * 4;
#pragma unroll
        for (int rb = 0; rb < 64; rb += 8) {
            int lrow = rb + ar;
            int row = m0 + lrow;
            ushort4 sv = make_ushort4(0, 0, 0, 0);
            if (ABF16_RELU) {
                if (row < M) {
                    ushort4 u = *(const ushort4*)((const unsigned short*)Av + (size_t)row * 128 + ac);
                    sv.x = bf_relu(u.x); sv.y = bf_relu(u.y);
                    sv.z = bf_relu(u.z); sv.w = bf_relu(u.w);
                }
            } else {
                if (row < M) {
                    float4 v = *(const float4*)((const float*)Av + (size_t)row * 128 + ac);
                    sv.x = f2bf(v.x); sv.y = f2bf(v.y); sv.z = f2bf(v.z); sv.w = f2bf(v.w);
                }
            }
            *(ushort4*)&As[lrow * KP + ac] = sv;
        }
    }
    {
        constexpr int TPR = N / 4;
        constexpr int KPI = 256 / TPR;
        int bk = t / TPR;
        int bn = (t % TPR) * 4;
#pragma unroll
        for (int kb = 0; kb < 128; kb += KPI) {
            int k = kb + bk;
            float4 wv = *(const float4*)(W + (size_t)k * N + bn);
            Bs[(bn + 0) * KP + k] = f2bf(wv.x);
            Bs[(bn + 1) * KP + k] = f2bf(wv.y);
            Bs[(bn + 2) * KP + k] = f2bf(wv.z);
            Bs[(bn + 3) * KP + k] = f2bf(wv.w);
        }
    }
    if (t < 64) sDin[t] = (m0 + t < M) ? dinv[m0 + t] : 1.0f;
    __syncthreads();

    const int w = t >> 6;
    const int lane = t & 63;
    const int lm = lane & 15;
    const int qd = lane >> 4;
    const int n0w = w * 16 * NT;

    f32x4 acc[4][NT];
#pragma unroll
    for (int mi = 0; mi < 4; ++mi)
#pragma unroll
        for (int ni = 0; ni < NT; ++ni) acc[mi][ni] = (f32x4){0.f, 0.f, 0.f, 0.f};

#pragma unroll
    for (int ks = 0; ks < 4; ++ks) {
        bf16x8 a[4], b[NT];
#pragma unroll
        for (int mi = 0; mi < 4; ++mi)
            a[mi] = *(const bf16x8*)&As[(mi * 16 + lm) * KP + ks * 32 + qd * 8];
#pragma unroll
        for (int ni = 0; ni < NT; ++ni)
            b[ni] = *(const bf16x8*)&Bs[(n0w + ni * 16 + lm) * KP + ks * 32 + qd * 8];
#pragma unroll
        for (int mi = 0; mi < 4; ++mi)
#pragma unroll
            for (int ni = 0; ni < NT; ++ni)
                acc[mi][ni] = __builtin_amdgcn_mfma_f32_16x16x32_bf16(a[mi], b[ni], acc[mi][ni], 0, 0, 0);
    }

#pragma unroll
    for (int mi = 0; mi < 4; ++mi) {
#pragma unroll
        for (int ni = 0; ni < NT; ++ni) {
            int col = n0w + ni * 16 + lm;
#pragma unroll
            for (int r = 0; r < 4; ++r) {
                int lrow = mi * 16 + qd * 4 + r;
                int row = m0 + lrow;
                if (row < M) C[(size_t)row * N + col] = f2bf(sDin[lrow] * acc[mi][ni][r]);
            }
        }
    }
}

// ---------------- CSR gather: out[d] = dinv[d] * (sum_in h'[src] + h'[d]) + b --------
// rp/deg addressing (padded windows are gapped). Unroll-16 + 8/4/2/1 ladder.

__global__ __launch_bounds__(256) void k_gather128(const int* __restrict__ rp,
                                                   const int* __restrict__ deg,
                                                   const int* __restrict__ eperm,
                                                   const float* __restrict__ dinv,
                                                   const unsigned int* __restrict__ h,  // bf16x2
                                                   const float* __restrict__ bias,
                                                   unsigned int* __restrict__ out,      // bf16x2
                                                   int n) {
    int node = blockIdx.x * 4 + (threadIdx.x >> 6);
    if (node >= n) return;
    int lane = threadIdx.x & 63;
    int beg = rp[node];
    int end = beg + deg[node];
    float2 acc = bf2_to_f2(h[(size_t)node * 64 + lane]);  // self h'[d]
    int j = beg;
    for (; j + 16 <= end; j += 16) {
        float2 a0 = make_float2(0.f, 0.f), a1 = a0;
#pragma unroll
        for (int u = 0; u < 2; ++u) {
            int e0 = eperm[j + 8 * u],     e1 = eperm[j + 8 * u + 1];
            int e2 = eperm[j + 8 * u + 2], e3 = eperm[j + 8 * u + 3];
            int e4 = eperm[j + 8 * u + 4], e5 = eperm[j + 8 * u + 5];
            int e6 = eperm[j + 8 * u + 6], e7 = eperm[j + 8 * u + 7];
            float2 v0 = bf2_to_f2(h[(size_t)e0 * 64 + lane]);
            float2 v1 = bf2_to_f2(h[(size_t)e1 * 64 + lane]);
            float2 v2 = bf2_to_f2(h[(size_t)e2 * 64 + lane]);
            float2 v3 = bf2_to_f2(h[(size_t)e3 * 64 + lane]);
            float2 v4 = bf2_to_f2(h[(size_t)e4 * 64 + lane]);
            float2 v5 = bf2_to_f2(h[(size_t)e5 * 64 + lane]);
            float2 v6 = bf2_to_f2(h[(size_t)e6 * 64 + lane]);
            float2 v7 = bf2_to_f2(h[(size_t)e7 * 64 + lane]);
            float2* dst2 = u ? &a1 : &a0;
            dst2->x += ((v0.x + v1.x) + (v2.x + v3.x)) + ((v4.x + v5.x) + (v6.x + v7.x));
            dst2->y += ((v0.y + v1.y) + (v2.y + v3.y)) + ((v4.y + v5.y) + (v6.y + v7.y));
        }
        acc.x += a0.x + a1.x;
        acc.y += a0.y + a1.y;
    }
    if (j + 8 <= end) {
        int e0 = eperm[j],     e1 = eperm[j + 1], e2 = eperm[j + 2], e3 = eperm[j + 3];
        int e4 = eperm[j + 4], e5 = eperm[j + 5], e6 = eperm[j + 6], e7 = eperm[j + 7];
        float2 v0 = bf2_to_f2(h[(size_t)e0 * 64 + lane]);
        float2 v1 = bf2_to_f2(h[(size_t)e1 * 64 + lane]);
        float2 v2 = bf2_to_f2(h[(size_t)e2 * 64 + lane]);
        float2 v3 = bf2_to_f2(h[(size_t)e3 * 64 + lane]);
        float2 v4 = bf2_to_f2(h[(size_t)e4 * 64 + lane]);
        float2 v5 = bf2_to_f2(h[(size_t)e5 * 64 + lane]);
        float2 v6 = bf2_to_f2(h[(size_t)e6 * 64 + lane]);
        float2 v7 = bf2_to_f2(h[(size_t)e7 * 64 + lane]);
        acc.x += ((v0.x + v1.x) + (v2.x + v3.x)) + ((v4.x + v5.x) + (v6.x + v7.x));
        acc.y += ((v0.y + v1.y) + (v2.y + v3.y)) + ((v4.y + v5.y) + (v6.y + v7.y));
        j += 8;
    }
    if (j + 4 <= end) {
        int e0 = eperm[j], e1 = eperm[j + 1], e2 = eperm[j + 2], e3 = eperm[j + 3];
        float2 v0 = bf2_to_f2(h[(size_t)e0 * 64 + lane]);
        float2 v1 = bf2_to_f2(h[(size_t)e1 * 64 + lane]);
        float2 v2 = bf2_to_f2(h[(size_t)e2 * 64 + lane]);
        float2 v3 = bf2_to_f2(h[(size_t)e3 * 64 + lane]);
        acc.x += (v0.x + v1.x) + (v2.x + v3.x);
        acc.y += (v0.y + v1.y) + (v2.y + v3.y);
        j += 4;
    }
    if (j + 2 <= end) {
        int e0 = eperm[j], e1 = eperm[j + 1];
        float2 v0 = bf2_to_f2(h[(size_t)e0 * 64 + lane]);
        float2 v1 = bf2_to_f2(h[(size_t)e1 * 64 + lane]);
        acc.x += v0.x + v1.x;
        acc.y += v0.y + v1.y;
        j += 2;
    }
    if (j < end) {
        float2 v = bf2_to_f2(h[(size_t)eperm[j] * 64 + lane]);
        acc.x += v.x;
        acc.y += v.y;
    }
    float dv = dinv[node];
    float2 bv = ((const float2*)bias)[lane];
    out[(size_t)node * 64 + lane] = pack_bf2(dv * acc.x + bv.x, dv * acc.y + bv.y);
}

// 64-wide: half-waves split the edge list (even/odd); unroll 8 per half.
__global__ __launch_bounds__(256) void k_gather64(const int* __restrict__ rp,
                                                  const int* __restrict__ deg,
                                                  const int* __restrict__ eperm,
                                                  const float* __restrict__ dinv,
                                                  const unsigned int* __restrict__ h,  // bf16x2
                                                  const float* __restrict__ bias,
                                                  float* __restrict__ out, int n) {
    int node = blockIdx.x * 4 + (threadIdx.x >> 6);
    if (node >= n) return;
    int t = threadIdx.x;
    int l32 = t & 31;
    int half = (t >> 5) & 1;
    int beg = rp[node];
    int end = beg + deg[node];
    float2 acc = make_float2(0.f, 0.f);
    if (half == 0) acc = bf2_to_f2(h[(size_t)node * 32 + l32]);  // self h'[d]
    int j = beg + half;
    for (; j + 14 < end; j += 16) {
        int e0 = eperm[j],      e1 = eperm[j + 2],  e2 = eperm[j + 4],  e3 = eperm[j + 6];
        int e4 = eperm[j + 8],  e5 = eperm[j + 10], e6 = eperm[j + 12], e7 = eperm[j + 14];
        float2 v0 = bf2_to_f2(h[(size_t)e0 * 32 + l32]);
        float2 v1 = bf2_to_f2(h[(size_t)e1 * 32 + l32]);
        float2 v2 = bf2_to_f2(h[(size_t)e2 * 32 + l32]);
        float2 v3 = bf2_to_f2(h[(size_t)e3 * 32 + l32]);
        float2 v4 = bf2_to_f2(h[(size_t)e4 * 32 + l32]);
        float2 v5 = bf2_to_f2(h[(size_t)e5 * 32 + l32]);
        float2 v6 = bf2_to_f2(h[(size_t)e6 * 32 + l32]);
        float2 v7 = bf2_to_f2(h[(size_t)e7 * 32 + l32]);
        acc.x += ((v0.x + v1.x) + (v2.x + v3.x)) + ((v4.x + v5.x) + (v6.x + v7.x));
        acc.y += ((v0.y + v1.y) + (v2.y + v3.y)) + ((v4.y + v5.y) + (v6.y + v7.y));
    }
    if (j + 6 < end) {
        int e0 = eperm[j], e1 = eperm[j + 2], e2 = eperm[j + 4], e3 = eperm[j + 6];
        float2 v0 = bf2_to_f2(h[(size_t)e0 * 32 + l32]);
        float2 v1 = bf2_to_f2(h[(size_t)e1 * 32 + l32]);
        float2 v2 = bf2_to_f2(h[(size_t)e2 * 32 + l32]);
        float2 v3 = bf2_to_f2(h[(size_t)e3 * 32 + l32]);
        acc.x += (v0.x + v1.x) + (v2.x + v3.x);
        acc.y += (v0.y + v1.y) + (v2.y + v3.y);
        j += 8;
    }
    for (; j < end; j += 2) {
        float2 v = bf2_to_f2(h[(size_t)eperm[j] * 32 + l32]);
        acc.x += v.x;
        acc.y += v.y;
    }
    acc.x += __shfl_xor(acc.x, 32);
    acc.y += __shfl_xor(acc.y, 32);
    if (half == 0) {
        float dv = dinv[node];
        float2 bv = ((const float2*)bias)[l32];
        ((float2*)out)[(size_t)node * 32 + l32] =
            make_float2(dv * acc.x + bv.x, dv * acc.y + bv.y);
    }
}

// ---------------- launch ----------------

extern "C" void kernel_launch(void* const* d_in, const int* in_sizes, int n_in,
                              void* d_out, int out_size, void* d_ws, size_t ws_size,
                              hipStream_t stream) {
    const float* x  = (const float*)d_in[0];
    const int*   ei = (const int*)d_in[1];
    const float* W1 = (const float*)d_in[2];
    const float* b1 = (const float*)d_in[3];
    const float* W2 = (const float*)d_in[4];
    const float* b2 = (const float*)d_in[5];
    float* out = (float*)d_out;

    const int N = in_sizes[0] / 128;
    const int E = in_sizes[1] / 2;
    const int* src = ei;
    const int* dst = ei + E;
    const int NB = (N + 511) >> BSHIFT;                          // coarse buckets (<= 256)
    const int cap = (E + NB - 1) / NB + ((E / NB) >> 2) + 1024;  // padded window (mean+25%+1024)

    char* ws = (char*)d_ws;
    size_t off = 0;
    auto carve = [&](size_t bytes) -> void* {
        void* p = ws + off;
        off = (off + bytes + 255) & ~(size_t)255;
        return p;
    };
    float* dinv = (float*)carve((size_t)N * 4);
    int*   rp   = (int*)carve((size_t)N * 4);
    int*   deg  = (int*)carve((size_t)N * 4);
    int*   bcur = (int*)carve(256 * 4);
    unsigned int* binned = (unsigned int*)carve((size_t)NB * cap * 4);  // packed (dlocal,src)
    int*   eperm = (int*)carve((size_t)NB * cap * 4);                   // src, bucket-windowed
    unsigned short* h    = (unsigned short*)carve((size_t)N * 128 * 2); // bf16 h' = dinv*(x@W1)
    unsigned short* hagg = (unsigned short*)carve((size_t)N * 128 * 2); // bf16 layer-1 out
    unsigned short* h2 = h;  // h dead after gather128

    const int gMm = (N + 63) / 64;
    const int ngrp = (N + 3) / 4;

    // ---- CSR build (2 kernels + 1 memset, padded windows) ----
    hipMemsetAsync(bcur, 0, 256 * sizeof(int), stream);
    k_bin<<<(E + BIN_CHUNK - 1) / BIN_CHUNK, THREADS, 0, stream>>>(src, dst, bcur, binned, E, NB, cap);
    k_node_place<<<NB, THREADS, 0, stream>>>(binned, bcur, cap, rp, deg, dinv, eperm, N);

    // ---- layer 1 ----
    k_gemm_mfma<128, false><<<gMm, THREADS, 0, stream>>>(x, W1, dinv, h, N);
    k_gather128<<<ngrp, THREADS, 0, stream>>>(rp, deg, eperm, dinv, (const unsigned int*)h, b1,
                                              (unsigned int*)hagg, N);

    // ---- layer 2 ----
    k_gemm_mfma<64, true><<<gMm, THREADS, 0, stream>>>(hagg, W2, dinv, h2, N);
    k_gather64<<<ngrp, THREADS, 0, stream>>>(rp, deg, eperm, dinv, (const unsigned int*)h2, b2, out, N);
}